// Round 6
// baseline (2751.284 us; speedup 1.0000x reference)
//
#include <hip/hip_runtime.h>
#include <hip/hip_cooperative_groups.h>
#include <math.h>

namespace cg = cooperative_groups;

#define NN 50000
#define NE 600000
#define HID 128
#define NCLS 10
#define MMBK 32
#define NTILE 391    // (NN+127)/128
#define NCHUNK 196   // (NN+255)/256
#define NGRP4 12500  // NN/4
#define NGRP16 3125  // NN/16

// ================= shared device bodies =================

__device__ __forceinline__ int wave_incl_scan(int x, int lane) {
#pragma unroll
    for (int off = 1; off < 64; off <<= 1) {
        int y = __shfl_up(x, off, 64);
        if (lane >= off) x += y;
    }
    return x;
}

// 128x128 tile SGEMM step: 256 thr, 8x8 per thread, BK=32 LDS staging (round-4 core).
__device__ __forceinline__ void dev_matmul_tile(const float* __restrict__ H,
                                                const float* __restrict__ W,
                                                float* __restrict__ T,
                                                int rowBase, int tid,
                                                float* As, float* Bs) {
    int lane = tid & 63, w = tid >> 6;
    int wr = lane >> 3, wc = lane & 7;
    int wy = w >> 1, wx = w & 1;
    int lr0 = wy * 64 + wr * 8;
    int lc0 = wx * 64 + wc * 8;

    int sa_row = tid >> 1;         // 0..127
    int sa_k = (tid & 1) * 16;     // 0 or 16
    int sa_grow = rowBase + sa_row;
    if (sa_grow >= NN) sa_grow = NN - 1;

    float acc[8][8];
#pragma unroll
    for (int i = 0; i < 8; ++i)
#pragma unroll
        for (int j = 0; j < 8; ++j) acc[i][j] = 0.f;

    for (int k0 = 0; k0 < HID; k0 += MMBK) {
        const float4* hsrc = (const float4*)(H + (size_t)sa_grow * HID + k0 + sa_k);
        float4 a0 = hsrc[0], a1 = hsrc[1], a2 = hsrc[2], a3 = hsrc[3];
        const float4* wsrc = (const float4*)(W + (size_t)k0 * HID);
        float4 b0 = wsrc[tid], b1 = wsrc[tid + 256], b2 = wsrc[tid + 512], b3 = wsrc[tid + 768];
        __syncthreads();  // previous iteration's/tile's LDS reads done
        As[(sa_k + 0) * 128 + sa_row] = a0.x;  As[(sa_k + 1) * 128 + sa_row] = a0.y;
        As[(sa_k + 2) * 128 + sa_row] = a0.z;  As[(sa_k + 3) * 128 + sa_row] = a0.w;
        As[(sa_k + 4) * 128 + sa_row] = a1.x;  As[(sa_k + 5) * 128 + sa_row] = a1.y;
        As[(sa_k + 6) * 128 + sa_row] = a1.z;  As[(sa_k + 7) * 128 + sa_row] = a1.w;
        As[(sa_k + 8) * 128 + sa_row] = a2.x;  As[(sa_k + 9) * 128 + sa_row] = a2.y;
        As[(sa_k + 10) * 128 + sa_row] = a2.z; As[(sa_k + 11) * 128 + sa_row] = a2.w;
        As[(sa_k + 12) * 128 + sa_row] = a3.x; As[(sa_k + 13) * 128 + sa_row] = a3.y;
        As[(sa_k + 14) * 128 + sa_row] = a3.z; As[(sa_k + 15) * 128 + sa_row] = a3.w;
        ((float4*)Bs)[tid] = b0;
        ((float4*)Bs)[tid + 256] = b1;
        ((float4*)Bs)[tid + 512] = b2;
        ((float4*)Bs)[tid + 768] = b3;
        __syncthreads();
#pragma unroll
        for (int kk = 0; kk < MMBK; ++kk) {
            float a[8], b[8];
            ((float4*)a)[0] = *(const float4*)&As[kk * 128 + lr0];
            ((float4*)a)[1] = *(const float4*)&As[kk * 128 + lr0 + 4];
            ((float4*)b)[0] = *(const float4*)&Bs[kk * 128 + lc0];
            ((float4*)b)[1] = *(const float4*)&Bs[kk * 128 + lc0 + 4];
#pragma unroll
            for (int i = 0; i < 8; ++i)
#pragma unroll
                for (int j = 0; j < 8; ++j) acc[i][j] += a[i] * b[j];
        }
    }
#pragma unroll
    for (int i = 0; i < 8; ++i) {
        int gr = rowBase + lr0 + i;
        if (gr < NN) {
            float4 o0 = {acc[i][0], acc[i][1], acc[i][2], acc[i][3]};
            float4 o1 = {acc[i][4], acc[i][5], acc[i][6], acc[i][7]};
            float4* dst = (float4*)(T + (size_t)gr * HID + lc0);
            dst[0] = o0;
            dst[1] = o1;
        }
    }
}

// one-wave-per-node gather + self-loop + bias + ELU (round-5 core)
__device__ __forceinline__ void dev_gather_node(const float* __restrict__ T,
                                                float* __restrict__ Hout,
                                                const int* __restrict__ rowptr,
                                                const int2* __restrict__ csr,
                                                const float* __restrict__ dinv,
                                                const float* __restrict__ bias,
                                                int node, int lane) {
    int slot = lane >> 4, c16 = lane & 15;
    int beg = rowptr[node], end = rowptr[node + 1];
    float4 acc0 = {0.f, 0.f, 0.f, 0.f}, acc1 = {0.f, 0.f, 0.f, 0.f};
    const int2 zed = make_int2(0, 0);  // weight bits 0 -> contributes 0

    int i = beg + slot;
    int2 e0 = (i < end) ? csr[i] : zed;
    int2 e1 = (i + 4 < end) ? csr[i + 4] : zed;
    for (; i < end; i += 8) {
        int2 p0 = (i + 8 < end) ? csr[i + 8] : zed;
        int2 p1 = (i + 12 < end) ? csr[i + 12] : zed;
        const float4* s0 = (const float4*)(T + (size_t)e0.x * HID);
        const float4* s1 = (const float4*)(T + (size_t)e1.x * HID);
        float4 u0 = s0[c16], u1 = s0[c16 + 16];
        float4 v0 = s1[c16], v1 = s1[c16 + 16];
        float w0 = __int_as_float(e0.y);
        float w1 = __int_as_float(e1.y);
        acc0.x += w0 * u0.x; acc0.y += w0 * u0.y; acc0.z += w0 * u0.z; acc0.w += w0 * u0.w;
        acc1.x += w0 * u1.x; acc1.y += w0 * u1.y; acc1.z += w0 * u1.z; acc1.w += w0 * u1.w;
        acc0.x += w1 * v0.x; acc0.y += w1 * v0.y; acc0.z += w1 * v0.z; acc0.w += w1 * v0.w;
        acc1.x += w1 * v1.x; acc1.y += w1 * v1.y; acc1.z += w1 * v1.z; acc1.w += w1 * v1.w;
        e0 = p0; e1 = p1;
    }
    acc0.x += __shfl_xor(acc0.x, 16, 64); acc0.y += __shfl_xor(acc0.y, 16, 64);
    acc0.z += __shfl_xor(acc0.z, 16, 64); acc0.w += __shfl_xor(acc0.w, 16, 64);
    acc1.x += __shfl_xor(acc1.x, 16, 64); acc1.y += __shfl_xor(acc1.y, 16, 64);
    acc1.z += __shfl_xor(acc1.z, 16, 64); acc1.w += __shfl_xor(acc1.w, 16, 64);
    acc0.x += __shfl_xor(acc0.x, 32, 64); acc0.y += __shfl_xor(acc0.y, 32, 64);
    acc0.z += __shfl_xor(acc0.z, 32, 64); acc0.w += __shfl_xor(acc0.w, 32, 64);
    acc1.x += __shfl_xor(acc1.x, 32, 64); acc1.y += __shfl_xor(acc1.y, 32, 64);
    acc1.z += __shfl_xor(acc1.z, 32, 64); acc1.w += __shfl_xor(acc1.w, 32, 64);

    if (slot == 0) {
        float sn = dinv[node];
        sn *= sn;
        const float4* trow = (const float4*)(T + (size_t)node * HID);
        float4 t0 = trow[c16], t1 = trow[c16 + 16];
        const float4* b4 = (const float4*)bias;
        float4 b0 = b4[c16], b1 = b4[c16 + 16];
        float4 r0, r1;
        r0.x = acc0.x + sn * t0.x + b0.x; r0.y = acc0.y + sn * t0.y + b0.y;
        r0.z = acc0.z + sn * t0.z + b0.z; r0.w = acc0.w + sn * t0.w + b0.w;
        r1.x = acc1.x + sn * t1.x + b1.x; r1.y = acc1.y + sn * t1.y + b1.y;
        r1.z = acc1.z + sn * t1.z + b1.z; r1.w = acc1.w + sn * t1.w + b1.w;
        r0.x = r0.x > 0.f ? r0.x : expm1f(r0.x);
        r0.y = r0.y > 0.f ? r0.y : expm1f(r0.y);
        r0.z = r0.z > 0.f ? r0.z : expm1f(r0.z);
        r0.w = r0.w > 0.f ? r0.w : expm1f(r0.w);
        r1.x = r1.x > 0.f ? r1.x : expm1f(r1.x);
        r1.y = r1.y > 0.f ? r1.y : expm1f(r1.y);
        r1.z = r1.z > 0.f ? r1.z : expm1f(r1.z);
        r1.w = r1.w > 0.f ? r1.w : expm1f(r1.w);
        float4* dst = (float4*)(Hout + (size_t)node * HID);
        dst[c16] = r0;
        dst[c16 + 16] = r1;
    }
}

// 128->10 matmul, W pre-staged in LDS (pad 11); 16 lanes per row
__device__ __forceinline__ void dev_outmat_row(const float* __restrict__ H,
                                               const float* __restrict__ Ws,
                                               float* __restrict__ T2,
                                               int row, int c16) {
    const float* h = H + (size_t)row * HID;
    float acc[NCLS];
#pragma unroll
    for (int c = 0; c < NCLS; ++c) acc[c] = 0.f;
#pragma unroll
    for (int j = 0; j < 8; ++j) {
        float hv = h[c16 + 16 * j];
        const float* wr = &Ws[(c16 + 16 * j) * 11];
#pragma unroll
        for (int c = 0; c < NCLS; ++c) acc[c] += hv * wr[c];
    }
#pragma unroll
    for (int off = 8; off >= 1; off >>= 1) {
#pragma unroll
        for (int c = 0; c < NCLS; ++c) acc[c] += __shfl_xor(acc[c], off, 16);
    }
    if (c16 < NCLS) T2[(size_t)row * NCLS + c16] = acc[c16];
}

__device__ __forceinline__ void dev_outgather_node(const float* __restrict__ T2,
                                                   float* __restrict__ out,
                                                   const int* __restrict__ rowptr,
                                                   const int2* __restrict__ csr,
                                                   const float* __restrict__ dinv,
                                                   const float* __restrict__ bias,
                                                   int node, int lane) {
    int slot = lane >> 4, c = lane & 15;
    int beg = rowptr[node], end = rowptr[node + 1];
    float acc = 0.f;
    if (c < NCLS) {
        for (int i = beg + slot; i < end; i += 4) {
            int2 e = csr[i];
            acc += __int_as_float(e.y) * T2[(size_t)e.x * NCLS + c];
        }
    }
    acc += __shfl_xor(acc, 16, 64);
    acc += __shfl_xor(acc, 32, 64);
    if (slot == 0 && c < NCLS) {
        float sn = dinv[node];
        sn *= sn;
        out[node * NCLS + c] = acc + sn * T2[(size_t)node * NCLS + c] + bias[c];
    }
}

// ================= cooperative mega-kernel =================
// __launch_bounds__(256,4): cap VGPR at 128 so 4 blocks/CU co-reside (LDS 32 KB -> 5/CU).

__global__ __launch_bounds__(256, 4) void k_mega(const float* __restrict__ x,
                                                 const int* __restrict__ edge,
                                                 const float* __restrict__ W_stack,
                                                 const float* __restrict__ b_stack,
                                                 const float* __restrict__ W_out,
                                                 const float* __restrict__ b_out,
                                                 float* __restrict__ out,
                                                 float* __restrict__ X,
                                                 float* __restrict__ Y,
                                                 int2* __restrict__ csr,
                                                 float* __restrict__ dinv,
                                                 int* __restrict__ rowptr,
                                                 int* __restrict__ counts,
                                                 int* __restrict__ bsum) {
    cg::grid_group gg = cg::this_grid();
    __shared__ float smem[8192];  // 32 KB union: {As|Bs} / scan ws / out-W
    float* As = smem;
    float* Bs = smem + MMBK * 128;
    int tid = threadIdx.x, bid = blockIdx.x;
    int gsz = gridDim.x * 256, gtid = bid * 256 + tid;

    // P0: zero counts  +  layer-0 matmul (independent of graph prep)
    for (int i = gtid; i < NN; i += gsz) counts[i] = 0;
    for (int t = bid; t < NTILE; t += gridDim.x)
        dev_matmul_tile(x, W_stack, Y, t * 128, tid, As, Bs);
    gg.sync();
    // P1: degree count
    for (int e = gtid; e < NE; e += gsz) atomicAdd(&counts[edge[NE + e]], 1);
    gg.sync();
    // P2: per-chunk scan + dinv
    {
        int* ws = (int*)smem;
        for (int c = bid; c < NCHUNK; c += gridDim.x) {
            int i = c * 256 + tid;
            int lane = tid & 63, wv = tid >> 6;
            int v = (i < NN) ? counts[i] : 0;
            if (i < NN) dinv[i] = rsqrtf((float)(v + 1));
            int xs = wave_incl_scan(v, lane);
            __syncthreads();
            if (lane == 63) ws[wv] = xs;
            __syncthreads();
            int off = 0;
            for (int j = 0; j < wv; ++j) off += ws[j];
            if (i < NN) rowptr[i] = off + xs - v;
            if (tid == 255) bsum[c] = off + xs;
        }
    }
    gg.sync();
    // P3: scan of chunk sums (block 0)
    if (bid == 0) {
        int* ws = (int*)smem;
        int lane = tid & 63, wv = tid >> 6;
        int v = (tid < NCHUNK) ? bsum[tid] : 0;
        int xs = wave_incl_scan(v, lane);
        if (lane == 63) ws[wv] = xs;
        __syncthreads();
        int off = 0;
        for (int j = 0; j < wv; ++j) off += ws[j];
        if (tid < NCHUNK) bsum[tid] = off + xs - v;
    }
    gg.sync();
    // P4: add chunk offsets + zero cursor
    for (int i = gtid; i < NN; i += gsz) {
        rowptr[i] += bsum[i >> 8];
        counts[i] = 0;
    }
    if (gtid == 0) rowptr[NN] = NE;
    gg.sync();
    // P5: CSR fill
    for (int e = gtid; e < NE; e += gsz) {
        int s = edge[e], d = edge[NE + e];
        int pq = rowptr[d] + atomicAdd(&counts[d], 1);
        csr[pq] = make_int2(s, __float_as_int(dinv[s] * dinv[d]));
    }
    gg.sync();
    // layers 1..7: gather(l-1) then matmul(l)
    for (int l = 1; l < 8; ++l) {
        const float* bias = b_stack + (size_t)(l - 1) * HID;
        for (int g = bid; g < NGRP4; g += gridDim.x)
            dev_gather_node(Y, X, rowptr, csr, dinv, bias, g * 4 + (tid >> 6), tid & 63);
        gg.sync();
        for (int t = bid; t < NTILE; t += gridDim.x)
            dev_matmul_tile(X, W_stack + (size_t)l * HID * HID, Y, t * 128, tid, As, Bs);
        gg.sync();
    }
    // gather for layer 8
    for (int g = bid; g < NGRP4; g += gridDim.x)
        dev_gather_node(Y, X, rowptr, csr, dinv, b_stack + 7 * HID, g * 4 + (tid >> 6), tid & 63);
    gg.sync();
    // out matmul (X @ W_out -> Y used as [NN,10])
    {
        float* Ws = smem;
        for (int m = tid; m < HID * NCLS; m += 256) {
            int k = m / NCLS, c = m - k * NCLS;
            Ws[k * 11 + c] = W_out[m];
        }
        __syncthreads();
        for (int g = bid; g < NGRP16; g += gridDim.x)
            dev_outmat_row(X, Ws, Y, g * 16 + (tid >> 4), tid & 15);
    }
    gg.sync();
    // out gather
    for (int g = bid; g < NGRP4; g += gridDim.x)
        dev_outgather_node(Y, out, rowptr, csr, dinv, b_out, g * 4 + (tid >> 6), tid & 63);
}

// ================= fallback multi-kernel path (round-4 structure) =================

__global__ __launch_bounds__(256) void k_count(const int* __restrict__ edge,
                                               int* __restrict__ counts) {
    int e = blockIdx.x * 256 + threadIdx.x;
    if (e < NE) atomicAdd(&counts[edge[NE + e]], 1);
}

__global__ __launch_bounds__(256) void k_zero(int* __restrict__ p, int n) {
    int i = blockIdx.x * 256 + threadIdx.x;
    if (i < n) p[i] = 0;
}

__global__ __launch_bounds__(256) void k_scan1(const int* __restrict__ counts,
                                               int* __restrict__ rowptr,
                                               int* __restrict__ bsum,
                                               float* __restrict__ dinv) {
    __shared__ int ws[4];
    int tid = threadIdx.x;
    int i = blockIdx.x * 256 + tid;
    int lane = tid & 63, wv = tid >> 6;
    int v = (i < NN) ? counts[i] : 0;
    if (i < NN) dinv[i] = rsqrtf((float)(v + 1));
    int x = wave_incl_scan(v, lane);
    if (lane == 63) ws[wv] = x;
    __syncthreads();
    int off = 0;
    for (int j = 0; j < wv; ++j) off += ws[j];
    if (i < NN) rowptr[i] = off + x - v;
    if (tid == 255) bsum[blockIdx.x] = off + x;
}

__global__ __launch_bounds__(256) void k_scan2(int* __restrict__ bsum, int n) {
    __shared__ int ws[4];
    int tid = threadIdx.x;
    int lane = tid & 63, wv = tid >> 6;
    int v = (tid < n) ? bsum[tid] : 0;
    int x = wave_incl_scan(v, lane);
    if (lane == 63) ws[wv] = x;
    __syncthreads();
    int off = 0;
    for (int j = 0; j < wv; ++j) off += ws[j];
    __syncthreads();
    if (tid < n) bsum[tid] = off + x - v;
}

__global__ __launch_bounds__(256) void k_scan3(int* __restrict__ rowptr,
                                               const int* __restrict__ bsum) {
    int i = blockIdx.x * 256 + threadIdx.x;
    if (i < NN) rowptr[i] += bsum[blockIdx.x];
    if (i == 0) rowptr[NN] = NE;
}

__global__ __launch_bounds__(256) void k_fill(const int* __restrict__ edge,
                                              const int* __restrict__ rowptr,
                                              int* __restrict__ cursor,
                                              const float* __restrict__ dinv,
                                              int2* __restrict__ csr) {
    int e = blockIdx.x * 256 + threadIdx.x;
    if (e >= NE) return;
    int s = edge[e], d = edge[NE + e];
    int p = rowptr[d] + atomicAdd(&cursor[d], 1);
    csr[p] = make_int2(s, __float_as_int(dinv[s] * dinv[d]));
}

__global__ __launch_bounds__(256) void k_matmul128(const float* __restrict__ H,
                                                   const float* __restrict__ W,
                                                   float* __restrict__ T) {
    __shared__ float As[MMBK * 128];
    __shared__ float Bs[MMBK * 128];
    dev_matmul_tile(H, W, T, blockIdx.x * 128, threadIdx.x, As, Bs);
}

__global__ __launch_bounds__(256) void k_gather_agg(const float* __restrict__ T,
                                                    float* __restrict__ Hout,
                                                    const int* __restrict__ rowptr,
                                                    const int2* __restrict__ csr,
                                                    const float* __restrict__ dinv,
                                                    const float* __restrict__ bias) {
    int node = (blockIdx.x * 256 + threadIdx.x) >> 6;
    if (node >= NN) return;
    dev_gather_node(T, Hout, rowptr, csr, dinv, bias, node, threadIdx.x & 63);
}

__global__ __launch_bounds__(256) void k_matmul_out(const float* __restrict__ H,
                                                    const float* __restrict__ W,
                                                    float* __restrict__ T2) {
    __shared__ float Ws[128 * 11];
    int tid = threadIdx.x;
    for (int m = tid; m < HID * NCLS; m += 256) {
        int k = m / NCLS, c = m - k * NCLS;
        Ws[k * 11 + c] = W[m];
    }
    __syncthreads();
    int row = (blockIdx.x * 256 + tid) >> 4;
    if (row >= NN) return;
    dev_outmat_row(H, Ws, T2, row, tid & 15);
}

__global__ __launch_bounds__(256) void k_gather_out(const float* __restrict__ T2,
                                                    float* __restrict__ out,
                                                    const int* __restrict__ rowptr,
                                                    const int2* __restrict__ csr,
                                                    const float* __restrict__ dinv,
                                                    const float* __restrict__ bias) {
    int node = (blockIdx.x * 256 + threadIdx.x) >> 6;
    if (node >= NN) return;
    dev_outgather_node(T2, out, rowptr, csr, dinv, bias, node, threadIdx.x & 63);
}

// ================= launch =================

extern "C" void kernel_launch(void* const* d_in, const int* in_sizes, int n_in,
                              void* d_out, int out_size, void* d_ws, size_t ws_size,
                              hipStream_t stream) {
    (void)in_sizes; (void)n_in; (void)out_size; (void)ws_size;
    const float* x       = (const float*)d_in[0];
    const int*   edge    = (const int*)d_in[1];
    const float* W_stack = (const float*)d_in[2];
    const float* b_stack = (const float*)d_in[3];
    const float* W_out   = (const float*)d_in[4];
    const float* b_out   = (const float*)d_in[5];
    float* out = (float*)d_out;

    char* ws = (char*)d_ws;
    const size_t bigbuf = (size_t)NN * HID * sizeof(float);  // 25.6 MB
    float* X      = (float*)ws;
    float* Y      = (float*)(ws + bigbuf);
    char*  p      = ws + 2 * bigbuf;
    int2*  csr    = (int2*)p;              p += sizeof(int2) * NE;
    float* dinv   = (float*)p;             p += sizeof(float) * NN;
    int*   rowptr = (int*)p;               p += sizeof(int) * (NN + 1);
    int*   counts = (int*)p;               p += sizeof(int) * NN;  // also cursor
    int*   bsum   = (int*)p;               p += sizeof(int) * 256;

    // ---- preferred: one cooperative mega-kernel ----
    int maxB = 0;
    hipError_t qerr = hipOccupancyMaxActiveBlocksPerMultiprocessor(&maxB, k_mega, 256, 0);
    if (qerr == hipSuccess && maxB >= 1) {
        int grid = maxB * 256;              // 256 CUs; deterministic across calls
        if (grid > 2048) grid = 2048;
        void* args[] = {(void*)&x,       (void*)&edge,  (void*)&W_stack, (void*)&b_stack,
                        (void*)&W_out,   (void*)&b_out, (void*)&out,     (void*)&X,
                        (void*)&Y,       (void*)&csr,   (void*)&dinv,    (void*)&rowptr,
                        (void*)&counts,  (void*)&bsum};
        hipError_t lerr = hipLaunchCooperativeKernel((const void*)k_mega, dim3(grid),
                                                     dim3(256), args, 0, stream);
        if (lerr == hipSuccess) return;
    }

    // ---- fallback: round-4 multi-kernel chain ----
    const int NB_N  = (NN + 255) / 256;
    const int NB_E  = (NE + 255) / 256;
    const int NB_MM = NTILE;
    const int NB_W  = (NN * 64 + 255) / 256;
    const int NB_O  = (NN * 16 + 255) / 256;

    k_zero<<<NB_N, 256, 0, stream>>>(counts, NN);
    k_count<<<NB_E, 256, 0, stream>>>(edge, counts);
    k_scan1<<<NB_N, 256, 0, stream>>>(counts, rowptr, bsum, dinv);
    k_scan2<<<1, 256, 0, stream>>>(bsum, NB_N);
    k_scan3<<<NB_N, 256, 0, stream>>>(rowptr, bsum);
    k_zero<<<NB_N, 256, 0, stream>>>(counts, NN);
    k_fill<<<NB_E, 256, 0, stream>>>(edge, rowptr, counts, dinv, csr);

    const float* Hin = x;
    for (int l = 0; l < 8; ++l) {
        k_matmul128<<<NB_MM, 256, 0, stream>>>(Hin, W_stack + (size_t)l * HID * HID, Y);
        k_gather_agg<<<NB_W, 256, 0, stream>>>(Y, X, rowptr, csr, dinv,
                                               b_stack + (size_t)l * HID);
        Hin = X;
    }
    k_matmul_out<<<NB_O, 256, 0, stream>>>(X, W_out, Y);
    k_gather_out<<<NB_W, 256, 0, stream>>>(Y, out, rowptr, csr, dinv, b_out);
}

// Round 7
// 1275.819 us; speedup vs baseline: 2.1565x; 2.1565x over previous
//
#include <hip/hip_runtime.h>
#include <math.h>

#define NN 50000
#define NE 600000
#define HID 128
#define NCLS 10
#define BK 32

// ================= graph prep: CSR by destination =================

__global__ __launch_bounds__(256) void k_zero(int* __restrict__ p, int n) {
    int i = blockIdx.x * 256 + threadIdx.x;
    if (i < n) p[i] = 0;
}

__global__ __launch_bounds__(256) void k_count(const int* __restrict__ edge,
                                               int* __restrict__ counts) {
    int e = blockIdx.x * 256 + threadIdx.x;
    if (e < NE) atomicAdd(&counts[edge[NE + e]], 1);
}

__device__ __forceinline__ int wave_incl_scan(int x, int lane) {
#pragma unroll
    for (int off = 1; off < 64; off <<= 1) {
        int y = __shfl_up(x, off, 64);
        if (lane >= off) x += y;
    }
    return x;
}

__global__ __launch_bounds__(256) void k_scan1(const int* __restrict__ counts,
                                               int* __restrict__ rowptr,
                                               int* __restrict__ bsum,
                                               float* __restrict__ dinv) {
    __shared__ int ws[4];
    int tid = threadIdx.x;
    int i = blockIdx.x * 256 + tid;
    int lane = tid & 63, wv = tid >> 6;
    int v = (i < NN) ? counts[i] : 0;
    if (i < NN) dinv[i] = rsqrtf((float)(v + 1));
    int x = wave_incl_scan(v, lane);
    if (lane == 63) ws[wv] = x;
    __syncthreads();
    int off = 0;
    for (int j = 0; j < wv; ++j) off += ws[j];
    if (i < NN) rowptr[i] = off + x - v;
    if (tid == 255) bsum[blockIdx.x] = off + x;
}

__global__ __launch_bounds__(256) void k_scan2(int* __restrict__ bsum, int n) {
    __shared__ int ws[4];
    int tid = threadIdx.x;
    int lane = tid & 63, wv = tid >> 6;
    int v = (tid < n) ? bsum[tid] : 0;
    int x = wave_incl_scan(v, lane);
    if (lane == 63) ws[wv] = x;
    __syncthreads();
    int off = 0;
    for (int j = 0; j < wv; ++j) off += ws[j];
    __syncthreads();
    if (tid < n) bsum[tid] = off + x - v;
}

__global__ __launch_bounds__(256) void k_scan3(int* __restrict__ rowptr,
                                               const int* __restrict__ bsum) {
    int i = blockIdx.x * 256 + threadIdx.x;
    if (i < NN) rowptr[i] += bsum[blockIdx.x];
    if (i == 0) rowptr[NN] = NE;
}

__global__ __launch_bounds__(256) void k_fill(const int* __restrict__ edge,
                                              const int* __restrict__ rowptr,
                                              int* __restrict__ cursor,
                                              const float* __restrict__ dinv,
                                              int2* __restrict__ csr) {
    int e = blockIdx.x * 256 + threadIdx.x;
    if (e >= NE) return;
    int s = edge[e], d = edge[NE + e];
    int p = rowptr[d] + atomicAdd(&cursor[d], 1);
    csr[p] = make_int2(s, __float_as_int(dinv[s] * dinv[d]));
}

// ========== dense: H[N,128] @ W[128,128] -> T (round-4 BK=32 SGEMM) ==========

__global__ __launch_bounds__(256) void k_matmul128(const float* __restrict__ H,
                                                   const float* __restrict__ W,
                                                   float* __restrict__ T) {
    __shared__ float As[BK * 128];
    __shared__ float Bs[BK * 128];
    int tid = threadIdx.x;
    int lane = tid & 63, w = tid >> 6;
    int wr = lane >> 3, wc = lane & 7;
    int wy = w >> 1, wx = w & 1;
    int lr0 = wy * 64 + wr * 8;
    int lc0 = wx * 64 + wc * 8;
    int rowBase = blockIdx.x * 128;

    int sa_row = tid >> 1;
    int sa_k = (tid & 1) * 16;
    int sa_grow = rowBase + sa_row;
    if (sa_grow >= NN) sa_grow = NN - 1;

    float acc[8][8];
#pragma unroll
    for (int i = 0; i < 8; ++i)
#pragma unroll
        for (int j = 0; j < 8; ++j) acc[i][j] = 0.f;

    for (int k0 = 0; k0 < HID; k0 += BK) {
        const float4* hsrc = (const float4*)(H + (size_t)sa_grow * HID + k0 + sa_k);
        float4 a0 = hsrc[0], a1 = hsrc[1], a2 = hsrc[2], a3 = hsrc[3];
        const float4* wsrc = (const float4*)(W + (size_t)k0 * HID);
        float4 b0 = wsrc[tid], b1 = wsrc[tid + 256], b2 = wsrc[tid + 512], b3 = wsrc[tid + 768];
        __syncthreads();
        As[(sa_k + 0) * 128 + sa_row] = a0.x;  As[(sa_k + 1) * 128 + sa_row] = a0.y;
        As[(sa_k + 2) * 128 + sa_row] = a0.z;  As[(sa_k + 3) * 128 + sa_row] = a0.w;
        As[(sa_k + 4) * 128 + sa_row] = a1.x;  As[(sa_k + 5) * 128 + sa_row] = a1.y;
        As[(sa_k + 6) * 128 + sa_row] = a1.z;  As[(sa_k + 7) * 128 + sa_row] = a1.w;
        As[(sa_k + 8) * 128 + sa_row] = a2.x;  As[(sa_k + 9) * 128 + sa_row] = a2.y;
        As[(sa_k + 10) * 128 + sa_row] = a2.z; As[(sa_k + 11) * 128 + sa_row] = a2.w;
        As[(sa_k + 12) * 128 + sa_row] = a3.x; As[(sa_k + 13) * 128 + sa_row] = a3.y;
        As[(sa_k + 14) * 128 + sa_row] = a3.z; As[(sa_k + 15) * 128 + sa_row] = a3.w;
        ((float4*)Bs)[tid] = b0;
        ((float4*)Bs)[tid + 256] = b1;
        ((float4*)Bs)[tid + 512] = b2;
        ((float4*)Bs)[tid + 768] = b3;
        __syncthreads();
#pragma unroll
        for (int kk = 0; kk < BK; ++kk) {
            float a[8], b[8];
            ((float4*)a)[0] = *(const float4*)&As[kk * 128 + lr0];
            ((float4*)a)[1] = *(const float4*)&As[kk * 128 + lr0 + 4];
            ((float4*)b)[0] = *(const float4*)&Bs[kk * 128 + lc0];
            ((float4*)b)[1] = *(const float4*)&Bs[kk * 128 + lc0 + 4];
#pragma unroll
            for (int i = 0; i < 8; ++i)
#pragma unroll
                for (int j = 0; j < 8; ++j) acc[i][j] += a[i] * b[j];
        }
    }
#pragma unroll
    for (int i = 0; i < 8; ++i) {
        int gr = rowBase + lr0 + i;
        if (gr < NN) {
            float4 o0 = {acc[i][0], acc[i][1], acc[i][2], acc[i][3]};
            float4 o1 = {acc[i][4], acc[i][5], acc[i][6], acc[i][7]};
            float4* dst = (float4*)(T + (size_t)gr * HID + lc0);
            dst[0] = o0;
            dst[1] = o1;
        }
    }
}

// ============ sparse gather: column-sliced, XCD-affine ============
// 8 slices of 16 cols; slice footprint of T = 3.2 MB -> fits one XCD's 4 MB L2.
// slice = blockIdx & 7: consecutive workgroups round-robin across the 8 XCDs,
// so each XCD's L2 mostly sees one slice (perf heuristic only; correctness is
// mapping-independent). Wave = 16 edge slots x 4 lanes x float4 -> 16 edges in
// flight; avg in-degree 12 -> usually a single iteration. Fused epilogue.

__global__ __launch_bounds__(256) void k_gather_slice(const float* __restrict__ T,
                                                      float* __restrict__ Hout,
                                                      const int* __restrict__ rowptr,
                                                      const int2* __restrict__ csr,
                                                      const float* __restrict__ dinv,
                                                      const float* __restrict__ bias) {
    int bid = blockIdx.x;
    int slice = bid & 7;       // -> XCD (round-robin heuristic)
    int nblk = bid >> 3;       // node block, 16 nodes per block (4 waves x 4 nodes)
    int wv = threadIdx.x >> 6, lane = threadIdx.x & 63;
    int slot = lane >> 2;      // 0..15 edge slot
    int l4 = lane & 3;         // float4 within the 16-col slice
    int col0 = slice * 16 + l4 * 4;
    float4 bb = *(const float4*)(bias + col0);

#pragma unroll
    for (int n = 0; n < 4; ++n) {
        int node = nblk * 16 + wv * 4 + n;   // NN = 3125*16 exact
        int beg = rowptr[node], end = rowptr[node + 1];
        float4 acc = {0.f, 0.f, 0.f, 0.f};
        for (int i = beg + slot; i < end; i += 16) {
            int2 e = csr[i];
            float w = __int_as_float(e.y);
            float4 v = *(const float4*)(T + (size_t)e.x * HID + col0);
            acc.x += w * v.x; acc.y += w * v.y; acc.z += w * v.z; acc.w += w * v.w;
        }
#pragma unroll
        for (int off = 4; off < 64; off <<= 1) {
            acc.x += __shfl_xor(acc.x, off, 64);
            acc.y += __shfl_xor(acc.y, off, 64);
            acc.z += __shfl_xor(acc.z, off, 64);
            acc.w += __shfl_xor(acc.w, off, 64);
        }
        if (slot == 0) {
            float sn = dinv[node];
            sn *= sn;
            float4 t = *(const float4*)(T + (size_t)node * HID + col0);
            float4 r;
            r.x = acc.x + sn * t.x + bb.x;
            r.y = acc.y + sn * t.y + bb.y;
            r.z = acc.z + sn * t.z + bb.z;
            r.w = acc.w + sn * t.w + bb.w;
            r.x = r.x > 0.f ? r.x : expm1f(r.x);
            r.y = r.y > 0.f ? r.y : expm1f(r.y);
            r.z = r.z > 0.f ? r.z : expm1f(r.z);
            r.w = r.w > 0.f ? r.w : expm1f(r.w);
            *(float4*)(Hout + (size_t)node * HID + col0) = r;
        }
    }
}

// ================= output layer (128 -> 10) =================

__global__ __launch_bounds__(256) void k_matmul_out(const float* __restrict__ H,
                                                    const float* __restrict__ W,
                                                    float* __restrict__ T2) {
    __shared__ float Ws[128 * 11];
    int tid = threadIdx.x;
    for (int m = tid; m < HID * NCLS; m += 256) {
        int k = m / NCLS, c = m - k * NCLS;
        Ws[k * 11 + c] = W[m];
    }
    __syncthreads();
    int row = (blockIdx.x * 256 + tid) >> 4;
    int c16 = tid & 15;
    if (row >= NN) return;
    const float* h = H + (size_t)row * HID;
    float acc[NCLS];
#pragma unroll
    for (int c = 0; c < NCLS; ++c) acc[c] = 0.f;
#pragma unroll
    for (int j = 0; j < 8; ++j) {
        float hv = h[c16 + 16 * j];
        const float* wr = &Ws[(c16 + 16 * j) * 11];
#pragma unroll
        for (int c = 0; c < NCLS; ++c) acc[c] += hv * wr[c];
    }
#pragma unroll
    for (int off = 8; off >= 1; off >>= 1) {
#pragma unroll
        for (int c = 0; c < NCLS; ++c) acc[c] += __shfl_xor(acc[c], off, 16);
    }
    if (c16 < NCLS) T2[(size_t)row * NCLS + c16] = acc[c16];
}

__global__ __launch_bounds__(256) void k_gather_out(const float* __restrict__ T2,
                                                    float* __restrict__ out,
                                                    const int* __restrict__ rowptr,
                                                    const int2* __restrict__ csr,
                                                    const float* __restrict__ dinv,
                                                    const float* __restrict__ bias) {
    int lane = threadIdx.x & 63;
    int node = (blockIdx.x * 256 + threadIdx.x) >> 6;
    if (node >= NN) return;
    int slot = lane >> 4, c = lane & 15;
    int beg = rowptr[node], end = rowptr[node + 1];
    float acc = 0.f;
    if (c < NCLS) {
        for (int i = beg + slot; i < end; i += 4) {
            int2 e = csr[i];
            acc += __int_as_float(e.y) * T2[(size_t)e.x * NCLS + c];
        }
    }
    acc += __shfl_xor(acc, 16, 64);
    acc += __shfl_xor(acc, 32, 64);
    if (slot == 0 && c < NCLS) {
        float sn = dinv[node];
        sn *= sn;
        out[node * NCLS + c] = acc + sn * T2[(size_t)node * NCLS + c] + bias[c];
    }
}

// ================= launch =================

extern "C" void kernel_launch(void* const* d_in, const int* in_sizes, int n_in,
                              void* d_out, int out_size, void* d_ws, size_t ws_size,
                              hipStream_t stream) {
    (void)in_sizes; (void)n_in; (void)out_size; (void)ws_size;
    const float* x       = (const float*)d_in[0];
    const int*   edge    = (const int*)d_in[1];   // [2, NE] int32
    const float* W_stack = (const float*)d_in[2];
    const float* b_stack = (const float*)d_in[3];
    const float* W_out   = (const float*)d_in[4];
    const float* b_out   = (const float*)d_in[5];
    float* out = (float*)d_out;

    char* ws = (char*)d_ws;
    const size_t bigbuf = (size_t)NN * HID * sizeof(float);  // 25.6 MB
    float* X      = (float*)ws;
    float* Y      = (float*)(ws + bigbuf);
    char*  p      = ws + 2 * bigbuf;
    int2*  csr    = (int2*)p;              p += sizeof(int2) * NE;
    float* dinv   = (float*)p;             p += sizeof(float) * NN;
    int*   rowptr = (int*)p;               p += sizeof(int) * (NN + 1);
    int*   counts = (int*)p;               p += sizeof(int) * NN;    // also cursor
    int*   bsum   = (int*)p;               p += sizeof(int) * 256;

    const int NB_N  = (NN + 255) / 256;        // 196
    const int NB_E  = (NE + 255) / 256;
    const int NB_MM = (NN + 127) / 128;        // 391
    const int NB_G  = 8 * (NN / 16);           // 8 slices x 3125 node-blocks = 25000
    const int NB_W  = (NN * 64 + 255) / 256;
    const int NB_O  = (NN * 16 + 255) / 256;

    // ---- CSR build (per call) ----
    k_zero<<<NB_N, 256, 0, stream>>>(counts, NN);
    k_count<<<NB_E, 256, 0, stream>>>(edge, counts);
    k_scan1<<<NB_N, 256, 0, stream>>>(counts, rowptr, bsum, dinv);
    k_scan2<<<1, 256, 0, stream>>>(bsum, NB_N);
    k_scan3<<<NB_N, 256, 0, stream>>>(rowptr, bsum);
    k_zero<<<NB_N, 256, 0, stream>>>(counts, NN);
    k_fill<<<NB_E, 256, 0, stream>>>(edge, rowptr, counts, dinv, csr);

    // ---- 8 hidden layers ----
    const float* Hin = x;
    for (int l = 0; l < 8; ++l) {
        k_matmul128<<<NB_MM, 256, 0, stream>>>(Hin, W_stack + (size_t)l * HID * HID, Y);
        k_gather_slice<<<NB_G, 256, 0, stream>>>(Y, X, rowptr, csr, dinv,
                                                 b_stack + (size_t)l * HID);
        Hin = X;
    }

    // ---- output layer ----
    k_matmul_out<<<NB_O, 256, 0, stream>>>(X, W_out, Y);
    k_gather_out<<<NB_W, 256, 0, stream>>>(Y, out, rowptr, csr, dinv, b_out);
}